// Round 1
// baseline (2681.194 us; speedup 1.0000x reference)
//
#include <hip/hip_runtime.h>
#include <hip/hip_bf16.h>
#include <math.h>

typedef unsigned int uint;
typedef unsigned short ushort;
typedef __attribute__((ext_vector_type(8))) short short8;
typedef __attribute__((ext_vector_type(4))) float f32x4;

#define NROWS 131072           // B*H*W = 2*256*256
#define SCALE_Q 0.18257418583505536f   // 30^-0.5

__device__ __forceinline__ float bf2f(ushort u) {
    union { uint i; float f; } v; v.i = ((uint)u) << 16; return v.f;
}
__device__ __forceinline__ ushort f2bf(float f) {
    union { float f; uint i; } v; v.f = f;
    uint i = v.i;
    uint r = (i + 0x7fffu + ((i >> 16) & 1u)) >> 16;
    return (ushort)r;
}

// ---------------------------------------------------------------------------
// Prep: transpose+pad+bf16 weights, pad biases, pre-gather attention bias
// ---------------------------------------------------------------------------
__global__ void prep_kernel(const int* __restrict__ rpi, const float* __restrict__ rpb,
                            const float* __restrict__ qkv_w, const float* __restrict__ qkv_b,
                            const float* __restrict__ proj_w, const float* __restrict__ proj_b,
                            const float* __restrict__ w1, const float* __restrict__ b1,
                            const float* __restrict__ w2, const float* __restrict__ b2,
                            float* __restrict__ bias_all,
                            ushort* __restrict__ wq_t, ushort* __restrict__ wp_t,
                            ushort* __restrict__ w1_t, ushort* __restrict__ w2_t,
                            float* __restrict__ bq, float* __restrict__ bp,
                            float* __restrict__ b1p, float* __restrict__ b2p)
{
    int i = blockIdx.x * 256 + threadIdx.x;
    if (i < 884736) {  // bias_all[6][256][576]
        int h = i / (256 * 576); int r = i % (256 * 576);
        int q = r / 576, k = r % 576;
        bias_all[(h * 256 + q) * 576 + k] = rpb[rpi[q * 576 + k] * 6 + h];
        return;
    }
    i -= 884736;
    if (i < 576 * 192) { int n = i / 192, k = i % 192;
        wq_t[i] = (n < 540 && k < 180) ? f2bf(qkv_w[k * 540 + n]) : (ushort)0; return; }
    i -= 576 * 192;
    if (i < 192 * 192) { int n = i / 192, k = i % 192;
        wp_t[i] = (n < 180 && k < 180) ? f2bf(proj_w[k * 180 + n]) : (ushort)0; return; }
    i -= 192 * 192;
    if (i < 384 * 192) { int n = i / 192, k = i % 192;
        w1_t[i] = (n < 360 && k < 180) ? f2bf(w1[k * 360 + n]) : (ushort)0; return; }
    i -= 384 * 192;
    if (i < 192 * 384) { int n = i / 384, k = i % 384;
        w2_t[i] = (n < 180 && k < 360) ? f2bf(w2[k * 180 + n]) : (ushort)0; return; }
    i -= 192 * 384;
    if (i < 576) { bq[i] = (i < 540) ? qkv_b[i] : 0.f; return; }
    i -= 576;
    if (i < 192) { bp[i] = (i < 180) ? proj_b[i] : 0.f; return; }
    i -= 192;
    if (i < 384) { b1p[i] = (i < 360) ? b1[i] : 0.f; return; }
    i -= 384;
    if (i < 192) { b2p[i] = (i < 180) ? b2[i] : 0.f; return; }
}

// ---------------------------------------------------------------------------
// LayerNorm: f32 [rows][180] -> bf16 [rows][192] (pads left as-is, weights
// are zero-padded so garbage*0 = 0 in downstream GEMMs)
// ---------------------------------------------------------------------------
__global__ void ln_kernel(const float* __restrict__ x, const float* __restrict__ g,
                          const float* __restrict__ b, ushort* __restrict__ out)
{
    int row = blockIdx.x * 4 + (threadIdx.x >> 6);
    int lane = threadIdx.x & 63;
    const float* xr = x + (long)row * 180;
    float v0 = xr[lane];
    float v1 = xr[lane + 64];
    float v2 = (lane < 52) ? xr[lane + 128] : 0.f;
    float s = v0 + v1 + v2;
    float ss = v0 * v0 + v1 * v1 + v2 * v2;
    #pragma unroll
    for (int m = 1; m < 64; m <<= 1) { s += __shfl_xor(s, m); ss += __shfl_xor(ss, m); }
    float mu = s * (1.f / 180.f);
    float var = ss * (1.f / 180.f) - mu * mu;
    float rs = rsqrtf(var + 1e-5f);
    ushort* orow = out + (long)row * 192;
    orow[lane]      = f2bf((v0 - mu) * rs * g[lane] + b[lane]);
    orow[lane + 64] = f2bf((v1 - mu) * rs * g[lane + 64] + b[lane + 64]);
    if (lane < 52)
        orow[lane + 128] = f2bf((v2 - mu) * rs * g[lane + 128] + b[lane + 128]);
}

// ---------------------------------------------------------------------------
// GEMM: A [131072 x KP] bf16 row-major, Bt [N x KP] bf16 row-major (pre-
// transposed weights). 128x64 tile, BK=32, 4 waves each 64x32 (4x2 frags).
// EPI 0: out bf16 = acc+bias, stride 576 (qkv)
// EPI 1: out f32  = acc+bias+aux, stride 180, col<180 (proj/mlp2 + residual)
// EPI 2: out bf16 = gelu(acc+bias), stride 384 (mlp1)
// ---------------------------------------------------------------------------
template<int KP, int EPI>
__global__ __launch_bounds__(256)
void gemm_kernel(const ushort* __restrict__ A, const ushort* __restrict__ Bt,
                 const float* __restrict__ bias, void* __restrict__ outp,
                 const float* __restrict__ aux)
{
    __shared__ ushort As[128 * 32];
    __shared__ ushort Bs[64 * 32];
    const int m0 = blockIdx.y * 128;
    const int n0 = blockIdx.x * 64;
    const int tid = threadIdx.x;
    const int lane = tid & 63;
    const int w = tid >> 6;
    const int wr = w >> 1, wc = w & 1;

    f32x4 acc[4][2] = {};

    const int arow = tid >> 2;
    const int acol = (tid & 3) * 8;
    const ushort* gA = A + (long)(m0 + arow) * KP + acol;
    const ushort* gB = Bt + (long)(n0 + arow) * KP + acol;

    typedef const __attribute__((address_space(1))) char* gp_t;
    typedef __attribute__((address_space(3))) char* lp_t;

    const int kg = (lane >> 4) * 8;
    const int rA = wr * 64 + (lane & 15);
    const int rB = wc * 32 + (lane & 15);

    for (int k0 = 0; k0 < KP; k0 += 32) {
        __builtin_amdgcn_global_load_lds((gp_t)(const char*)(gA + k0),
                                         (lp_t)(char*)(As + tid * 8), 16, 0, 0);
        __builtin_amdgcn_global_load_lds((gp_t)(const char*)(gA + 64 * KP + k0),
                                         (lp_t)(char*)(As + 2048 + tid * 8), 16, 0, 0);
        __builtin_amdgcn_global_load_lds((gp_t)(const char*)(gB + k0),
                                         (lp_t)(char*)(Bs + tid * 8), 16, 0, 0);
        __syncthreads();
        short8 a[4], bb[2];
        #pragma unroll
        for (int mi = 0; mi < 4; ++mi)
            a[mi] = *(const short8*)&As[(rA + mi * 16) * 32 + kg];
        #pragma unroll
        for (int ni = 0; ni < 2; ++ni)
            bb[ni] = *(const short8*)&Bs[(rB + ni * 16) * 32 + kg];
        #pragma unroll
        for (int mi = 0; mi < 4; ++mi)
            #pragma unroll
            for (int ni = 0; ni < 2; ++ni)
                acc[mi][ni] = __builtin_amdgcn_mfma_f32_16x16x32_bf16(
                    a[mi], bb[ni], acc[mi][ni], 0, 0, 0);
        __syncthreads();
    }

    #pragma unroll
    for (int mi = 0; mi < 4; ++mi) {
        #pragma unroll
        for (int ni = 0; ni < 2; ++ni) {
            int col = n0 + wc * 32 + ni * 16 + (lane & 15);
            int rbase = m0 + wr * 64 + mi * 16 + (lane >> 4) * 4;
            float bcol = bias[col];
            #pragma unroll
            for (int r = 0; r < 4; ++r) {
                long row = rbase + r;
                float v = acc[mi][ni][r] + bcol;
                if (EPI == 0) {
                    ((ushort*)outp)[row * 576 + col] = f2bf(v);
                } else if (EPI == 1) {
                    if (col < 180)
                        ((float*)outp)[row * 180 + col] = v + aux[row * 180 + col];
                } else {
                    float t = 0.5f * v * (1.f + erff(v * 0.70710678118654752f));
                    ((ushort*)outp)[row * 384 + col] = f2bf(t);
                }
            }
        }
    }
}

// ---------------------------------------------------------------------------
// Attention: block = (window, head). 256 threads, thread = one q row.
// K/V (24x24 overlapping window, zero-padded at image border) staged f32 in
// LDS. Online-softmax flash over 18 chunks of 32 keys. bias pre-gathered.
// ---------------------------------------------------------------------------
__global__ __launch_bounds__(256)
void attn_kernel(const ushort* __restrict__ qkv, const float* __restrict__ bias_all,
                 ushort* __restrict__ obuf)
{
    __shared__ float kf[576][32];
    __shared__ float vf[576][32];
    const int blk = blockIdx.x;
    const int head = blk % 6;
    const int win = blk / 6;
    const int wj = win & 15, wi = (win >> 4) & 15, b = win >> 8;
    const int t = threadIdx.x;

    for (int idx = t; idx < 576; idx += 256) {
        int iy = idx / 24, ix = idx % 24;
        int gy = wi * 16 - 4 + iy, gx = wj * 16 - 4 + ix;
        if (gy >= 0 && gy < 256 && gx >= 0 && gx < 256) {
            const ushort* src = qkv + ((long)((b * 256 + gy) * 256 + gx)) * 576 + 180 + head * 30;
            const uint* sk = (const uint*)src;
            const uint* sv = (const uint*)(src + 180);
            #pragma unroll
            for (int u = 0; u < 15; ++u) {
                uint pk = sk[u], pv = sv[u];
                kf[idx][2 * u]     = bf2f((ushort)(pk & 0xffff));
                kf[idx][2 * u + 1] = bf2f((ushort)(pk >> 16));
                vf[idx][2 * u]     = bf2f((ushort)(pv & 0xffff));
                vf[idx][2 * u + 1] = bf2f((ushort)(pv >> 16));
            }
        } else {
            #pragma unroll
            for (int u = 0; u < 30; ++u) { kf[idx][u] = 0.f; vf[idx][u] = 0.f; }
        }
    }
    __syncthreads();

    const int r = t >> 4, cc = t & 15;
    const long grow = (long)((b * 256 + wi * 16 + r) * 256 + wj * 16 + cc);
    const uint* qsrc = (const uint*)(qkv + grow * 576 + head * 30);
    float q[30];
    #pragma unroll
    for (int u = 0; u < 15; ++u) {
        uint p = qsrc[u];
        q[2 * u]     = bf2f((ushort)(p & 0xffff)) * SCALE_Q;
        q[2 * u + 1] = bf2f((ushort)(p >> 16)) * SCALE_Q;
    }
    const float* brow = bias_all + ((long)(head * 256 + t)) * 576;

    float m = -1e30f, l = 0.f;
    float o[30];
    #pragma unroll
    for (int u = 0; u < 30; ++u) o[u] = 0.f;

    for (int ch = 0; ch < 18; ++ch) {
        float s[32];
        const float4* b4 = (const float4*)(brow + ch * 32);
        #pragma unroll
        for (int u = 0; u < 8; ++u) {
            float4 bv = b4[u];
            s[4 * u] = bv.x; s[4 * u + 1] = bv.y; s[4 * u + 2] = bv.z; s[4 * u + 3] = bv.w;
        }
        float cmax = -1e30f;
        #pragma unroll
        for (int j2 = 0; j2 < 32; ++j2) {
            const float* kr = kf[ch * 32 + j2];
            const float4* k4 = (const float4*)kr;
            float d0 = 0.f, d1 = 0.f, d2 = 0.f, d3 = 0.f;
            #pragma unroll
            for (int u = 0; u < 7; ++u) {
                float4 kk = k4[u];
                d0 += q[4 * u] * kk.x;     d1 += q[4 * u + 1] * kk.y;
                d2 += q[4 * u + 2] * kk.z; d3 += q[4 * u + 3] * kk.w;
            }
            float2 kt = ((const float2*)kr)[14];
            d0 += q[28] * kt.x; d1 += q[29] * kt.y;
            s[j2] += (d0 + d1) + (d2 + d3);
            cmax = fmaxf(cmax, s[j2]);
        }
        float mn = fmaxf(m, cmax);
        float corr = __expf(m - mn);
        l *= corr;
        #pragma unroll
        for (int u = 0; u < 30; ++u) o[u] *= corr;
        #pragma unroll
        for (int j2 = 0; j2 < 32; ++j2) {
            float p = __expf(s[j2] - mn);
            l += p;
            const float* vr = vf[ch * 32 + j2];
            const float4* v4 = (const float4*)vr;
            #pragma unroll
            for (int u = 0; u < 7; ++u) {
                float4 vv = v4[u];
                o[4 * u] += p * vv.x;     o[4 * u + 1] += p * vv.y;
                o[4 * u + 2] += p * vv.z; o[4 * u + 3] += p * vv.w;
            }
            float2 vt = ((const float2*)vr)[14];
            o[28] += p * vt.x; o[29] += p * vt.y;
        }
        m = mn;
    }
    float inv = 1.f / l;
    uint* dst = (uint*)(obuf + grow * 192 + head * 30);
    #pragma unroll
    for (int u = 0; u < 15; ++u) {
        uint lo = f2bf(o[2 * u] * inv);
        uint hi = f2bf(o[2 * u + 1] * inv);
        dst[u] = lo | (hi << 16);
    }
}

// ---------------------------------------------------------------------------
extern "C" void kernel_launch(void* const* d_in, const int* in_sizes, int n_in,
                              void* d_out, int out_size, void* d_ws, size_t ws_size,
                              hipStream_t stream)
{
    const float* x      = (const float*)d_in[0];
    const int*   rpi    = (const int*)d_in[1];
    const float* qkv_w  = (const float*)d_in[2];
    const float* qkv_b  = (const float*)d_in[3];
    const float* proj_w = (const float*)d_in[4];
    const float* proj_b = (const float*)d_in[5];
    const float* rpb    = (const float*)d_in[6];
    const float* ln1_g  = (const float*)d_in[7];
    const float* ln1_b  = (const float*)d_in[8];
    const float* ln2_g  = (const float*)d_in[9];
    const float* ln2_b  = (const float*)d_in[10];
    const float* w1     = (const float*)d_in[11];
    const float* b1     = (const float*)d_in[12];
    const float* w2     = (const float*)d_in[13];
    const float* b2     = (const float*)d_in[14];
    float* out = (float*)d_out;
    char* ws = (char*)d_ws;

    // ws layout (all 256-aligned)
    ushort* wq_t     = (ushort*)(ws + 0);          // 576*192*2   = 221184
    ushort* wp_t     = (ushort*)(ws + 221184);     // 192*192*2   = 73728
    ushort* w1_t     = (ushort*)(ws + 294912);     // 384*192*2   = 147456
    ushort* w2_t     = (ushort*)(ws + 442368);     // 192*384*2   = 147456
    float*  bq       = (float*)(ws + 589824);      // 576*4
    float*  bp       = (float*)(ws + 592128);      // 192*4
    float*  b1p      = (float*)(ws + 592896);      // 384*4
    float*  b2p      = (float*)(ws + 594432);      // 192*4
    float*  bias_all = (float*)(ws + 595200);      // 6*256*576*4 = 3538944
    ushort* hbuf     = (ushort*)(ws + 4194304);    // 131072*192*2 = 50331648 (h, then h2)
    ushort* qkv      = (ushort*)(ws + 54525952);   // 131072*576*2 = 150994944
    float*  x2f      = (float*)(ws + 54525952);    // overlays qkv after attention
    ushort* obuf     = (ushort*)(ws + 205520896);  // 131072*192*2 = 50331648
    ushort* g1       = (ushort*)(ws + 205520896);  // overlays obuf: 131072*384*2
    // total: 306,184,192 bytes

    prep_kernel<<<4614, 256, 0, stream>>>(rpi, rpb, qkv_w, qkv_b, proj_w, proj_b,
                                          w1, b1, w2, b2, bias_all,
                                          wq_t, wp_t, w1_t, w2_t, bq, bp, b1p, b2p);
    ln_kernel<<<32768, 256, 0, stream>>>(x, ln1_g, ln1_b, hbuf);
    gemm_kernel<192, 0><<<dim3(9, 1024), 256, 0, stream>>>(hbuf, wq_t, bq, qkv, nullptr);
    attn_kernel<<<3072, 256, 0, stream>>>(qkv, bias_all, obuf);
    gemm_kernel<192, 1><<<dim3(3, 1024), 256, 0, stream>>>(obuf, wp_t, bp, x2f, x);
    ln_kernel<<<32768, 256, 0, stream>>>(x2f, ln2_g, ln2_b, hbuf);
    gemm_kernel<192, 2><<<dim3(6, 1024), 256, 0, stream>>>(hbuf, w1_t, b1p, g1, nullptr);
    gemm_kernel<384, 1><<<dim3(3, 1024), 256, 0, stream>>>(g1, w2_t, b2p, out, x2f);
}

// Round 7
// 754.533 us; speedup vs baseline: 3.5534x; 3.5534x over previous
//
#include <hip/hip_runtime.h>
#include <hip/hip_bf16.h>
#include <math.h>

typedef unsigned int uint;
typedef unsigned short ushort;
typedef __attribute__((ext_vector_type(8))) short short8;
typedef __attribute__((ext_vector_type(4))) float f32x4;

#define NROWS 131072           // B*H*W = 2*256*256
#define SCALE_Q 0.18257418583505536f          // 30^-0.5
#define SCALE_Q2 (0.18257418583505536f * 1.4426950408889634f)  // *log2(e)
#define LOG2E 1.4426950408889634f

__device__ __forceinline__ float bf2f(ushort u) {
    union { uint i; float f; } v; v.i = ((uint)u) << 16; return v.f;
}
__device__ __forceinline__ ushort f2bf(float f) {
    union { float f; uint i; } v; v.f = f;
    uint i = v.i;
    uint r = (i + 0x7fffu + ((i >> 16) & 1u)) >> 16;
    return (ushort)r;
}

// ---------------------------------------------------------------------------
// Prep: transpose+pad+bf16 weights, pad biases, pre-gather attention bias
// bias_t layout: [head][576 key][256 q] f32, pre-scaled by log2(e)
// qkv-padded layout downstream: row stride 576, slot = seg*192 + head*32 + d
// ---------------------------------------------------------------------------
__global__ void prep_kernel(const int* __restrict__ rpi, const float* __restrict__ rpb,
                            const float* __restrict__ qkv_w, const float* __restrict__ qkv_b,
                            const float* __restrict__ proj_w, const float* __restrict__ proj_b,
                            const float* __restrict__ w1, const float* __restrict__ b1,
                            const float* __restrict__ w2, const float* __restrict__ b2,
                            float* __restrict__ bias_t,
                            ushort* __restrict__ wq_t, ushort* __restrict__ wp_t,
                            ushort* __restrict__ w1_t, ushort* __restrict__ w2_t,
                            float* __restrict__ bq, float* __restrict__ bp,
                            float* __restrict__ b1p, float* __restrict__ b2p)
{
    int i = blockIdx.x * 256 + threadIdx.x;
    if (i < 884736) {  // bias_t[6][576][256]
        int h = i / (576 * 256); int r = i % (576 * 256);
        int k = r / 256, q = r % 256;
        bias_t[(h * 576 + k) * 256 + q] = rpb[rpi[q * 576 + k] * 6 + h] * LOG2E;
        return;
    }
    i -= 884736;
    if (i < 576 * 192) { int n = i / 192, k = i % 192;
        wq_t[i] = (n < 540 && k < 180) ? f2bf(qkv_w[k * 540 + n]) : (ushort)0; return; }
    i -= 576 * 192;
    if (i < 192 * 192) { int n = i / 192, k = i % 192;
        int h = k >> 5, d = k & 31;
        wp_t[i] = (n < 180 && d < 30) ? f2bf(proj_w[(h * 30 + d) * 180 + n]) : (ushort)0; return; }
    i -= 192 * 192;
    if (i < 384 * 192) { int n = i / 192, k = i % 192;
        w1_t[i] = (n < 360 && k < 180) ? f2bf(w1[k * 360 + n]) : (ushort)0; return; }
    i -= 384 * 192;
    if (i < 192 * 384) { int n = i / 384, k = i % 384;
        w2_t[i] = (n < 180 && k < 360) ? f2bf(w2[k * 180 + n]) : (ushort)0; return; }
    i -= 192 * 384;
    if (i < 576) { bq[i] = (i < 540) ? qkv_b[i] : 0.f; return; }
    i -= 576;
    if (i < 192) { bp[i] = (i < 180) ? proj_b[i] : 0.f; return; }
    i -= 192;
    if (i < 384) { b1p[i] = (i < 360) ? b1[i] : 0.f; return; }
    i -= 384;
    if (i < 192) { b2p[i] = (i < 180) ? b2[i] : 0.f; return; }
}

// Zero the d=30,31 pad slots of the padded qkv buffer.
__global__ void padzero_kernel(ushort* __restrict__ qkv)
{
    int i = blockIdx.x * 256 + threadIdx.x;
    if (i < 131072 * 18) {
        int row = i / 18, s = i % 18;
        int seg = s / 6, h = s % 6;
        *(uint*)(qkv + (long)row * 576 + seg * 192 + h * 32 + 30) = 0;
    }
}

// ---------------------------------------------------------------------------
// LayerNorm: f32 [rows][180] -> bf16 [rows][192]; pad cols 180..191 ZEROED
// (they are staged into MFMA A operands; stale NaN x 0 = NaN).
// ---------------------------------------------------------------------------
__global__ void ln_kernel(const float* __restrict__ x, const float* __restrict__ g,
                          const float* __restrict__ b, ushort* __restrict__ out)
{
    int row = blockIdx.x * 4 + (threadIdx.x >> 6);
    int lane = threadIdx.x & 63;
    const float* xr = x + (long)row * 180;
    float v0 = xr[lane];
    float v1 = xr[lane + 64];
    float v2 = (lane < 52) ? xr[lane + 128] : 0.f;
    float s = v0 + v1 + v2;
    float ss = v0 * v0 + v1 * v1 + v2 * v2;
    #pragma unroll
    for (int m = 1; m < 64; m <<= 1) { s += __shfl_xor(s, m); ss += __shfl_xor(ss, m); }
    float mu = s * (1.f / 180.f);
    float var = ss * (1.f / 180.f) - mu * mu;
    float rs = rsqrtf(var + 1e-5f);
    ushort* orow = out + (long)row * 192;
    orow[lane]      = f2bf((v0 - mu) * rs * g[lane] + b[lane]);
    orow[lane + 64] = f2bf((v1 - mu) * rs * g[lane + 64] + b[lane + 64]);
    orow[lane + 128] = (lane < 52)
        ? f2bf((v2 - mu) * rs * g[lane + 128] + b[lane + 128])
        : (ushort)0;
}

// ---------------------------------------------------------------------------
// GEMM: A [131072 x KP] bf16 row-major, Bt [N x KP] bf16 row-major.
// EPI 0: out bf16 = acc+bias, padded qkv layout (col<540 -> seg*192+h*32+d)
// EPI 1: out f32  = acc+bias+aux, stride 180, col<180
// EPI 2: out bf16 = gelu(acc+bias), stride 384
// ---------------------------------------------------------------------------
template<int KP, int EPI>
__global__ __launch_bounds__(256)
void gemm_kernel(const ushort* __restrict__ A, const ushort* __restrict__ Bt,
                 const float* __restrict__ bias, void* __restrict__ outp,
                 const float* __restrict__ aux)
{
    __shared__ ushort As[128 * 32];
    __shared__ ushort Bs[64 * 32];
    const int m0 = blockIdx.y * 128;
    const int n0 = blockIdx.x * 64;
    const int tid = threadIdx.x;
    const int lane = tid & 63;
    const int w = tid >> 6;
    const int wr = w >> 1, wc = w & 1;

    f32x4 acc[4][2] = {};

    const int arow = tid >> 2;
    const int acol = (tid & 3) * 8;
    const ushort* gA = A + (long)(m0 + arow) * KP + acol;
    const ushort* gB = Bt + (long)(n0 + arow) * KP + acol;

    typedef const __attribute__((address_space(1))) char* gp_t;
    typedef __attribute__((address_space(3))) char* lp_t;

    const int kg = (lane >> 4) * 8;
    const int rA = wr * 64 + (lane & 15);
    const int rB = wc * 32 + (lane & 15);

    for (int k0 = 0; k0 < KP; k0 += 32) {
        __builtin_amdgcn_global_load_lds((gp_t)(const char*)(gA + k0),
                                         (lp_t)(char*)(As + tid * 8), 16, 0, 0);
        __builtin_amdgcn_global_load_lds((gp_t)(const char*)(gA + 64 * KP + k0),
                                         (lp_t)(char*)(As + 2048 + tid * 8), 16, 0, 0);
        __builtin_amdgcn_global_load_lds((gp_t)(const char*)(gB + k0),
                                         (lp_t)(char*)(Bs + tid * 8), 16, 0, 0);
        __syncthreads();
        short8 a[4], bb[2];
        #pragma unroll
        for (int mi = 0; mi < 4; ++mi)
            a[mi] = *(const short8*)&As[(rA + mi * 16) * 32 + kg];
        #pragma unroll
        for (int ni = 0; ni < 2; ++ni)
            bb[ni] = *(const short8*)&Bs[(rB + ni * 16) * 32 + kg];
        #pragma unroll
        for (int mi = 0; mi < 4; ++mi)
            #pragma unroll
            for (int ni = 0; ni < 2; ++ni)
                acc[mi][ni] = __builtin_amdgcn_mfma_f32_16x16x32_bf16(
                    a[mi], bb[ni], acc[mi][ni], 0, 0, 0);
        __syncthreads();
    }

    #pragma unroll
    for (int mi = 0; mi < 4; ++mi) {
        #pragma unroll
        for (int ni = 0; ni < 2; ++ni) {
            int col = n0 + wc * 32 + ni * 16 + (lane & 15);
            int rbase = m0 + wr * 64 + mi * 16 + (lane >> 4) * 4;
            float bcol = bias[col];
            #pragma unroll
            for (int r = 0; r < 4; ++r) {
                long row = rbase + r;
                float v = acc[mi][ni][r] + bcol;
                if (EPI == 0) {
                    if (col < 540) {
                        int seg = col / 180;
                        int r2  = col - seg * 180;
                        int hh  = r2 / 30;
                        int dd  = r2 - hh * 30;
                        ((ushort*)outp)[row * 576 + seg * 192 + hh * 32 + dd] = f2bf(v);
                    }
                } else if (EPI == 1) {
                    if (col < 180)
                        ((float*)outp)[row * 180 + col] = v + aux[row * 180 + col];
                } else {
                    float t = 0.5f * v * (1.f + erff(v * 0.70710678118654752f));
                    ((ushort*)outp)[row * 384 + col] = f2bf(t);
                }
            }
        }
    }
}

// ---------------------------------------------------------------------------
// MFMA attention — CONSERVATIVE version. Block = (window, head), 4 waves,
// wave owns 64 q rows; 9 chunks of 64 keys; mfma_f32_16x16x32_bf16.
// All LDS layouts linear/padded, 16B-aligned strides, no swizzles, no
// global_load_lds, full __syncthreads() between P write and PV read.
// exp2 arg clamped to +-30: attn output is ALWAYS finite (bisection aid).
//  K_lds [key][40]  (data d in [0,32))
//  Vt_lds [d][72]   (data key in [0,64))
//  P_lds per-wave [q][64]
// ---------------------------------------------------------------------------
__global__ __launch_bounds__(256)
void attn_kernel(const ushort* __restrict__ qkv, const float* __restrict__ bias_t,
                 ushort* __restrict__ obuf)
{
    __shared__ ushort K_lds[64 * 40];
    __shared__ ushort Vt_lds[32 * 72];
    __shared__ ushort P_lds[4][64 * 64];

    const int blk = blockIdx.x;
    const int head = blk % 6;
    const int win = blk / 6;
    const int wj = win & 15, wi = (win >> 4) & 15, b = win >> 8;
    const int t = threadIdx.x;
    const int lane = t & 63;
    const int w = t >> 6;
    const int lg = lane >> 4;      // 0..3
    const int lc = lane & 15;

    // Q fragments: A-frag row (m) = lc, k = lg*8+j ; window q = w*64+mi*16+lc
    short8 qf[4];
    {
        const int x = wj * 16 + lc;
        #pragma unroll
        for (int mi = 0; mi < 4; ++mi) {
            int y = wi * 16 + w * 4 + mi;
            long grow = (long)(b * 256 + y) * 256 + x;
            qf[mi] = *(const short8*)(qkv + grow * 576 + head * 32 + lg * 8);
        }
    }

    ushort* Pw = P_lds[w];
    f32x4 oacc[4][2] = {};
    f32x4 lpart[4] = {};
    const f32x4 zz = {0.f, 0.f, 0.f, 0.f};
    const short8 zv = {0, 0, 0, 0, 0, 0, 0, 0};

    const int keyloc = t >> 2;   // chunk-local key staged by this thread
    const int p4 = t & 3;        // 16B d-block

    for (int ch = 0; ch < 9; ++ch) {
        // ---- stage K + V (register loads, branchless OOB-zero)
        {
            int kk = ch * 64 + keyloc;
            int ky = kk / 24, kx = kk - ky * 24;
            int gy = wi * 16 - 4 + ky, gx = wj * 16 - 4 + kx;
            bool ok = (gy >= 0 && gy < 256 && gx >= 0 && gx < 256);
            long grow = ok ? ((long)(b * 256 + gy) * 256 + gx) : 0;
            const ushort* base = qkv + grow * 576 + head * 32 + p4 * 8;
            short8 kvv = *(const short8*)(base + 192);
            short8 vvv = *(const short8*)(base + 384);
            if (!ok) { kvv = zv; vvv = zv; }
            *(short8*)&K_lds[keyloc * 40 + p4 * 8] = kvv;
            #pragma unroll
            for (int j = 0; j < 8; ++j)
                Vt_lds[(p4 * 8 + j) * 72 + keyloc] = ((const ushort*)&vvv)[j];
        }
        __syncthreads();

        // ---- QK^T: 16 MFMA (K plays Bt: col(n)=key by lc, k=d by lg)
        short8 kb[4];
        #pragma unroll
        for (int ni = 0; ni < 4; ++ni)
            kb[ni] = *(const short8*)&K_lds[(ni * 16 + lc) * 40 + lg * 8];
        f32x4 sacc[4][4];
        #pragma unroll
        for (int mi = 0; mi < 4; ++mi)
            #pragma unroll
            for (int ni = 0; ni < 4; ++ni)
                sacc[mi][ni] = __builtin_amdgcn_mfma_f32_16x16x32_bf16(
                    qf[mi], kb[ni], zz, 0, 0, 0);

        // ---- bias + exp2 (clamped) + P write + denominator partials
        #pragma unroll
        for (int mi = 0; mi < 4; ++mi) {
            int q0 = w * 64 + mi * 16 + lg * 4;      // window q of r=0
            #pragma unroll
            for (int ni = 0; ni < 4; ++ni) {
                int key = ch * 64 + ni * 16 + lc;
                f32x4 bv = *(const f32x4*)(bias_t + ((long)(head * 576 + key)) * 256 + q0);
                int kloc = ni * 16 + lc;
                #pragma unroll
                for (int r = 0; r < 4; ++r) {
                    float arg = fmaf(sacc[mi][ni][r], SCALE_Q2, bv[r]);
                    arg = fminf(fmaxf(arg, -30.f), 30.f);
                    float p = exp2f(arg);
                    lpart[mi][r] += p;
                    int q = mi * 16 + lg * 4 + r;    // wave-local q
                    Pw[q * 64 + kloc] = f2bf(p);
                }
            }
        }
        __syncthreads();

        // ---- PV: 16 MFMA (P is A: row(m)=q by lc; Vt is Bt: col(n)=d by lc)
        #pragma unroll
        for (int ks = 0; ks < 2; ++ks) {
            short8 vb[2];
            #pragma unroll
            for (int nj = 0; nj < 2; ++nj)
                vb[nj] = *(const short8*)&Vt_lds[(nj * 16 + lc) * 72 + ks * 32 + lg * 8];
            #pragma unroll
            for (int mi = 0; mi < 4; ++mi) {
                short8 pa = *(const short8*)&Pw[(mi * 16 + lc) * 64 + ks * 32 + lg * 8];
                #pragma unroll
                for (int nj = 0; nj < 2; ++nj)
                    oacc[mi][nj] = __builtin_amdgcn_mfma_f32_16x16x32_bf16(
                        pa, vb[nj], oacc[mi][nj], 0, 0, 0);
            }
        }
        __syncthreads();
    }

    // ---- denominator reduce (sum over lc lanes; lg preserved) + store
    #pragma unroll
    for (int mi = 0; mi < 4; ++mi) {
        #pragma unroll
        for (int r = 0; r < 4; ++r) {
            float v = lpart[mi][r];
            v += __shfl_xor(v, 1); v += __shfl_xor(v, 2);
            v += __shfl_xor(v, 4); v += __shfl_xor(v, 8);
            lpart[mi][r] = 1.f / v;
        }
    }
    #pragma unroll
    for (int mi = 0; mi < 4; ++mi) {
        int y = wi * 16 + w * 4 + mi;
        #pragma unroll
        for (int r = 0; r < 4; ++r) {
            int x = wj * 16 + lg * 4 + r;
            long grow = (long)(b * 256 + y) * 256 + x;
            float inv = lpart[mi][r];
            #pragma unroll
            for (int nj = 0; nj < 2; ++nj) {
                int d = nj * 16 + lc;
                obuf[grow * 192 + head * 32 + d] = f2bf(d < 30 ? oacc[mi][nj][r] * inv : 0.f);
            }
        }
    }
}

// ---------------------------------------------------------------------------
extern "C" void kernel_launch(void* const* d_in, const int* in_sizes, int n_in,
                              void* d_out, int out_size, void* d_ws, size_t ws_size,
                              hipStream_t stream)
{
    const float* x      = (const float*)d_in[0];
    const int*   rpi    = (const int*)d_in[1];
    const float* qkv_w  = (const float*)d_in[2];
    const float* qkv_b  = (const float*)d_in[3];
    const float* proj_w = (const float*)d_in[4];
    const float* proj_b = (const float*)d_in[5];
    const float* rpb    = (const float*)d_in[6];
    const float* ln1_g  = (const float*)d_in[7];
    const float* ln1_b  = (const float*)d_in[8];
    const float* ln2_g  = (const float*)d_in[9];
    const float* ln2_b  = (const float*)d_in[10];
    const float* w1     = (const float*)d_in[11];
    const float* b1     = (const float*)d_in[12];
    const float* w2     = (const float*)d_in[13];
    const float* b2     = (const float*)d_in[14];
    float* out = (float*)d_out;
    char* ws = (char*)d_ws;

    // ws layout (all 256-aligned)
    ushort* wq_t     = (ushort*)(ws + 0);          // 576*192*2   = 221184
    ushort* wp_t     = (ushort*)(ws + 221184);     // 192*192*2   = 73728
    ushort* w1_t     = (ushort*)(ws + 294912);     // 384*192*2   = 147456
    ushort* w2_t     = (ushort*)(ws + 442368);     // 192*384*2   = 147456
    float*  bq       = (float*)(ws + 589824);      // 576*4
    float*  bp       = (float*)(ws + 592128);      // 192*4
    float*  b1p      = (float*)(ws + 592896);      // 384*4
    float*  b2p      = (float*)(ws + 594432);      // 192*4
    float*  bias_t   = (float*)(ws + 595200);      // 6*576*256*4 = 3538944
    ushort* hbuf     = (ushort*)(ws + 4194304);    // 131072*192*2 = 50331648
    ushort* qkv      = (ushort*)(ws + 54525952);   // 131072*576*2 = 150994944 (padded layout)
    float*  x2f      = (float*)(ws + 54525952);    // overlays qkv after attention
    ushort* obuf     = (ushort*)(ws + 205520896);  // 131072*192*2 = 50331648
    ushort* g1       = (ushort*)(ws + 205520896);  // overlays obuf: 131072*384*2

    prep_kernel<<<4614, 256, 0, stream>>>(rpi, rpb, qkv_w, qkv_b, proj_w, proj_b,
                                          w1, b1, w2, b2, bias_t,
                                          wq_t, wp_t, w1_t, w2_t, bq, bp, b1p, b2p);
    padzero_kernel<<<9216, 256, 0, stream>>>(qkv);
    ln_kernel<<<32768, 256, 0, stream>>>(x, ln1_g, ln1_b, hbuf);
    gemm_kernel<192, 0><<<dim3(9, 1024), 256, 0, stream>>>(hbuf, wq_t, bq, qkv, nullptr);
    attn_kernel<<<3072, 256, 0, stream>>>(qkv, bias_t, obuf);
    gemm_kernel<192, 1><<<dim3(3, 1024), 256, 0, stream>>>(obuf, wp_t, bp, x2f, x);
    ln_kernel<<<32768, 256, 0, stream>>>(x2f, ln2_g, ln2_b, hbuf);
    gemm_kernel<192, 2><<<dim3(6, 1024), 256, 0, stream>>>(hbuf, w1_t, b1p, g1, nullptr);
    gemm_kernel<384, 1><<<dim3(3, 1024), 256, 0, stream>>>(g1, w2_t, b2p, out, x2f);
}

// Round 8
// 726.691 us; speedup vs baseline: 3.6896x; 1.0383x over previous
//
#include <hip/hip_runtime.h>
#include <hip/hip_bf16.h>
#include <math.h>

typedef unsigned int uint;
typedef unsigned short ushort;
typedef __attribute__((ext_vector_type(8))) short short8;
typedef __attribute__((ext_vector_type(4))) float f32x4;

#define NROWS 131072           // B*H*W = 2*256*256
#define SCALE_Q 0.18257418583505536f          // 30^-0.5
#define SCALE_Q2 (0.18257418583505536f * 1.4426950408889634f)  // *log2(e)
#define INV_SCALE_Q 5.477225575051661f        // sqrt(30)

__device__ __forceinline__ float bf2f(ushort u) {
    union { uint i; float f; } v; v.i = ((uint)u) << 16; return v.f;
}
__device__ __forceinline__ ushort f2bf(float f) {
    union { float f; uint i; } v; v.f = f;
    uint i = v.i;
    uint r = (i + 0x7fffu + ((i >> 16) & 1u)) >> 16;
    return (ushort)r;
}

// ---------------------------------------------------------------------------
// Prep: transpose+pad+bf16 weights, pad biases.
// qkv-padded layout downstream: row stride 576, slot = seg*192 + head*32 + d
// ---------------------------------------------------------------------------
__global__ void prep_kernel(const float* __restrict__ qkv_w, const float* __restrict__ qkv_b,
                            const float* __restrict__ proj_w, const float* __restrict__ proj_b,
                            const float* __restrict__ w1, const float* __restrict__ b1,
                            const float* __restrict__ w2, const float* __restrict__ b2,
                            ushort* __restrict__ wq_t, ushort* __restrict__ wp_t,
                            ushort* __restrict__ w1_t, ushort* __restrict__ w2_t,
                            float* __restrict__ bq, float* __restrict__ bp,
                            float* __restrict__ b1p, float* __restrict__ b2p)
{
    int i = blockIdx.x * 256 + threadIdx.x;
    if (i < 576 * 192) { int n = i / 192, k = i % 192;
        wq_t[i] = (n < 540 && k < 180) ? f2bf(qkv_w[k * 540 + n]) : (ushort)0; return; }
    i -= 576 * 192;
    if (i < 192 * 192) { int n = i / 192, k = i % 192;
        int h = k >> 5, d = k & 31;
        wp_t[i] = (n < 180 && d < 30) ? f2bf(proj_w[(h * 30 + d) * 180 + n]) : (ushort)0; return; }
    i -= 192 * 192;
    if (i < 384 * 192) { int n = i / 192, k = i % 192;
        w1_t[i] = (n < 360 && k < 180) ? f2bf(w1[k * 360 + n]) : (ushort)0; return; }
    i -= 384 * 192;
    if (i < 192 * 384) { int n = i / 384, k = i % 384;
        w2_t[i] = (n < 180 && k < 360) ? f2bf(w2[k * 180 + n]) : (ushort)0; return; }
    i -= 192 * 384;
    if (i < 576) { bq[i] = (i < 540) ? qkv_b[i] : 0.f; return; }
    i -= 576;
    if (i < 192) { bp[i] = (i < 180) ? proj_b[i] : 0.f; return; }
    i -= 192;
    if (i < 384) { b1p[i] = (i < 360) ? b1[i] : 0.f; return; }
    i -= 384;
    if (i < 192) { b2p[i] = (i < 180) ? b2[i] : 0.f; return; }
}

// ---------------------------------------------------------------------------
// Bias gather+transpose: bias_t[h][k][q] = rpb[rpi[q*576+k]*6+h] / SCALE_Q
// (pre-divided so it can enter QK^T as the MFMA C operand).
// Both global access sides coalesced via a 32x32 LDS tile.
// grid: 6 heads * 18 ktiles * 8 qtiles = 864 blocks
// ---------------------------------------------------------------------------
__global__ void biasprep_kernel(const int* __restrict__ rpi, const float* __restrict__ rpb,
                                float* __restrict__ bias_t)
{
    __shared__ float tile[32][33];
    int bid = blockIdx.x;
    int h = bid / 144;
    int rr = bid % 144;
    int k0 = (rr >> 3) * 32;     // 18 k tiles
    int q0 = (rr & 7) * 32;      // 8 q tiles
    int tl = threadIdx.x & 31;
    int ts = threadIdx.x >> 5;   // 0..7
    #pragma unroll
    for (int s = 0; s < 4; ++s) {
        int q = q0 + ts + s * 8;
        int k = k0 + tl;
        tile[ts + s * 8][tl] = rpb[rpi[q * 576 + k] * 6 + h] * INV_SCALE_Q;
    }
    __syncthreads();
    #pragma unroll
    for (int s = 0; s < 4; ++s) {
        int k = k0 + ts + s * 8;
        bias_t[((long)h * 576 + k) * 256 + q0 + tl] = tile[tl][ts + s * 8];
    }
}

// ---------------------------------------------------------------------------
// LayerNorm: f32 [rows][180] -> bf16 [rows][192]; pad cols 180..191 ZEROED
// (they are staged into MFMA A operands; stale NaN x 0 = NaN).
// ---------------------------------------------------------------------------
__global__ void ln_kernel(const float* __restrict__ x, const float* __restrict__ g,
                          const float* __restrict__ b, ushort* __restrict__ out)
{
    int row = blockIdx.x * 4 + (threadIdx.x >> 6);
    int lane = threadIdx.x & 63;
    const float* xr = x + (long)row * 180;
    float v0 = xr[lane];
    float v1 = xr[lane + 64];
    float v2 = (lane < 52) ? xr[lane + 128] : 0.f;
    float s = v0 + v1 + v2;
    float ss = v0 * v0 + v1 * v1 + v2 * v2;
    #pragma unroll
    for (int m = 1; m < 64; m <<= 1) { s += __shfl_xor(s, m); ss += __shfl_xor(ss, m); }
    float mu = s * (1.f / 180.f);
    float var = ss * (1.f / 180.f) - mu * mu;
    float rs = rsqrtf(var + 1e-5f);
    ushort* orow = out + (long)row * 192;
    orow[lane]      = f2bf((v0 - mu) * rs * g[lane] + b[lane]);
    orow[lane + 64] = f2bf((v1 - mu) * rs * g[lane + 64] + b[lane + 64]);
    orow[lane + 128] = (lane < 52)
        ? f2bf((v2 - mu) * rs * g[lane + 128] + b[lane + 128])
        : (ushort)0;
}

// ---------------------------------------------------------------------------
// GEMM: A [131072 x KP] bf16 row-major, Bt [N x KP] bf16 row-major.
// EPI 0: out bf16 = acc+bias, padded qkv layout; cols 540..575 land on the
//        d=30,31 pad slots (zero weights + zero bias -> writes 0, replacing
//        the old padzero kernel).
// EPI 1: out f32  = acc+bias+aux, stride 180, col<180
// EPI 2: out bf16 = gelu(acc+bias), stride 384
// ---------------------------------------------------------------------------
template<int KP, int EPI>
__global__ __launch_bounds__(256)
void gemm_kernel(const ushort* __restrict__ A, const ushort* __restrict__ Bt,
                 const float* __restrict__ bias, void* __restrict__ outp,
                 const float* __restrict__ aux)
{
    __shared__ ushort As[128 * 32];
    __shared__ ushort Bs[64 * 32];
    const int m0 = blockIdx.y * 128;
    const int n0 = blockIdx.x * 64;
    const int tid = threadIdx.x;
    const int lane = tid & 63;
    const int w = tid >> 6;
    const int wr = w >> 1, wc = w & 1;

    f32x4 acc[4][2] = {};

    const int arow = tid >> 2;
    const int acol = (tid & 3) * 8;
    const ushort* gA = A + (long)(m0 + arow) * KP + acol;
    const ushort* gB = Bt + (long)(n0 + arow) * KP + acol;

    typedef const __attribute__((address_space(1))) char* gp_t;
    typedef __attribute__((address_space(3))) char* lp_t;

    const int kg = (lane >> 4) * 8;
    const int rA = wr * 64 + (lane & 15);
    const int rB = wc * 32 + (lane & 15);

    for (int k0 = 0; k0 < KP; k0 += 32) {
        __builtin_amdgcn_global_load_lds((gp_t)(const char*)(gA + k0),
                                         (lp_t)(char*)(As + tid * 8), 16, 0, 0);
        __builtin_amdgcn_global_load_lds((gp_t)(const char*)(gA + 64 * KP + k0),
                                         (lp_t)(char*)(As + 2048 + tid * 8), 16, 0, 0);
        __builtin_amdgcn_global_load_lds((gp_t)(const char*)(gB + k0),
                                         (lp_t)(char*)(Bs + tid * 8), 16, 0, 0);
        __syncthreads();
        short8 a[4], bb[2];
        #pragma unroll
        for (int mi = 0; mi < 4; ++mi)
            a[mi] = *(const short8*)&As[(rA + mi * 16) * 32 + kg];
        #pragma unroll
        for (int ni = 0; ni < 2; ++ni)
            bb[ni] = *(const short8*)&Bs[(rB + ni * 16) * 32 + kg];
        #pragma unroll
        for (int mi = 0; mi < 4; ++mi)
            #pragma unroll
            for (int ni = 0; ni < 2; ++ni)
                acc[mi][ni] = __builtin_amdgcn_mfma_f32_16x16x32_bf16(
                    a[mi], bb[ni], acc[mi][ni], 0, 0, 0);
        __syncthreads();
    }

    #pragma unroll
    for (int mi = 0; mi < 4; ++mi) {
        #pragma unroll
        for (int ni = 0; ni < 2; ++ni) {
            int col = n0 + wc * 32 + ni * 16 + (lane & 15);
            int rbase = m0 + wr * 64 + mi * 16 + (lane >> 4) * 4;
            float bcol = bias[col];
            #pragma unroll
            for (int r = 0; r < 4; ++r) {
                long row = rbase + r;
                float v = acc[mi][ni][r] + bcol;
                if (EPI == 0) {
                    int seg, hh, dd;
                    if (col < 540) {
                        seg = col / 180; int r2 = col - seg * 180;
                        hh = r2 / 30; dd = r2 - hh * 30;
                    } else {
                        int s2 = col - 540;
                        seg = s2 / 12; int r3 = s2 - seg * 12;
                        hh = r3 >> 1; dd = 30 + (r3 & 1);
                    }
                    ((ushort*)outp)[row * 576 + seg * 192 + hh * 32 + dd] = f2bf(v);
                } else if (EPI == 1) {
                    if (col < 180)
                        ((float*)outp)[row * 180 + col] = v + aux[row * 180 + col];
                } else {
                    float t = 0.5f * v * (1.f + erff(v * 0.70710678118654752f));
                    ((ushort*)outp)[row * 384 + col] = f2bf(t);
                }
            }
        }
    }
}

// ---------------------------------------------------------------------------
// MFMA attention. Block = (window, head), 4 waves, wave owns 64 q rows;
// 9 chunks of 64 keys; mfma_f32_16x16x32_bf16.
//  - bias enters QK^T as the MFMA C operand (bias_t pre-divided by SCALE_Q)
//  - P stored truncated-bf16 in per-wave XOR-swizzled LDS (q*64 + (k^((q&7)<<3)))
//  - Vt XOR-swizzled [32 d][64 key]; row d=31 staged as 1.0 -> PV's d=31
//    output column IS the softmax denominator (no separate accumulation)
//  - register staging of K/V, full __syncthreads structure (verified base)
// ---------------------------------------------------------------------------
__global__ __launch_bounds__(256)
void attn_kernel(const ushort* __restrict__ qkv, const float* __restrict__ bias_t,
                 ushort* __restrict__ obuf)
{
    __shared__ ushort K_lds[64 * 40];
    __shared__ ushort Vt_lds[32 * 64];
    __shared__ ushort P_lds[4][64 * 64];

    const int blk = blockIdx.x;
    const int head = blk % 6;
    const int win = blk / 6;
    const int wj = win & 15, wi = (win >> 4) & 15, b = win >> 8;
    const int t = threadIdx.x;
    const int lane = t & 63;
    const int w = t >> 6;
    const int lg = lane >> 4;      // 0..3
    const int lc = lane & 15;

    // Q fragments: A-frag row (m) = lc, k = lg*8+j ; window q = w*64+mi*16+lc
    short8 qf[4];
    {
        const int x = wj * 16 + lc;
        #pragma unroll
        for (int mi = 0; mi < 4; ++mi) {
            int y = wi * 16 + w * 4 + mi;
            long grow = (long)(b * 256 + y) * 256 + x;
            qf[mi] = *(const short8*)(qkv + grow * 576 + head * 32 + lg * 8);
        }
    }

    ushort* Pw = P_lds[w];
    f32x4 oacc[4][2] = {};
    const short8 zv = {0, 0, 0, 0, 0, 0, 0, 0};

    const int keyloc = t >> 2;   // chunk-local key staged by this thread
    const int p4 = t & 3;        // 16B d-block

    // per-lane bias base: rows (C-frag) = w*64 + mi*16 + lg*4 + r
    const float* bias_base = bias_t + (long)head * 576 * 256 + (w * 64 + lg * 4);

    for (int ch = 0; ch < 9; ++ch) {
        // ---- stage K + V (register loads, branchless OOB-zero)
        {
            int kk = ch * 64 + keyloc;
            int ky = kk / 24, kx = kk - ky * 24;
            int gy = wi * 16 - 4 + ky, gx = wj * 16 - 4 + kx;
            bool ok = (gy >= 0 && gy < 256 && gx >= 0 && gx < 256);
            long grow = ok ? ((long)(b * 256 + gy) * 256 + gx) : 0;
            const ushort* base = qkv + grow * 576 + head * 32 + p4 * 8;
            short8 kvv = *(const short8*)(base + 192);
            short8 vvv = *(const short8*)(base + 384);
            if (!ok) { kvv = zv; vvv = zv; }
            *(short8*)&K_lds[keyloc * 40 + p4 * 8] = kvv;
            #pragma unroll
            for (int j = 0; j < 8; ++j) {
                int d = p4 * 8 + j;
                Vt_lds[d * 64 + (keyloc ^ ((d & 7) << 3))] = ((const ushort*)&vvv)[j];
            }
            if (p4 == 3)  // ones column at d=31 (denominator via PV MFMA)
                Vt_lds[31 * 64 + (keyloc ^ 56)] = (ushort)0x3F80;
        }
        __syncthreads();

        // ---- QK^T (bias as C-in): 16 MFMA, then P = exp2(s*SCALE_Q2)
        short8 kb[4];
        #pragma unroll
        for (int ni = 0; ni < 4; ++ni)
            kb[ni] = *(const short8*)&K_lds[(ni * 16 + lc) * 40 + lg * 8];
        #pragma unroll
        for (int mi = 0; mi < 4; ++mi) {
            #pragma unroll
            for (int ni = 0; ni < 4; ++ni) {
                f32x4 bv = *(const f32x4*)(bias_base
                              + ((long)(ch * 64 + ni * 16 + lc)) * 256 + mi * 16);
                f32x4 s = __builtin_amdgcn_mfma_f32_16x16x32_bf16(
                    qf[mi], kb[ni], bv, 0, 0, 0);
                int kloc = ni * 16 + lc;
                #pragma unroll
                for (int r = 0; r < 4; ++r) {
                    float p = exp2f(s[r] * SCALE_Q2);
                    int q = mi * 16 + lg * 4 + r;    // wave-local q
                    uint bits = __builtin_bit_cast(uint, p);
                    Pw[q * 64 + (kloc ^ ((q & 7) << 3))] = (ushort)(bits >> 16);
                }
            }
        }
        __syncthreads();

        // ---- PV: 16 MFMA
        #pragma unroll
        for (int ks = 0; ks < 2; ++ks) {
            short8 vb[2];
            #pragma unroll
            for (int nj = 0; nj < 2; ++nj) {
                int d = nj * 16 + lc;
                vb[nj] = *(const short8*)&Vt_lds[d * 64
                              + ((ks * 32 + lg * 8) ^ ((d & 7) << 3))];
            }
            #pragma unroll
            for (int mi = 0; mi < 4; ++mi) {
                int q = mi * 16 + lc;
                short8 pa = *(const short8*)&Pw[q * 64
                              + ((ks * 32 + lg * 8) ^ ((q & 7) << 3))];
                #pragma unroll
                for (int nj = 0; nj < 2; ++nj)
                    oacc[mi][nj] = __builtin_amdgcn_mfma_f32_16x16x32_bf16(
                        pa, vb[nj], oacc[mi][nj], 0, 0, 0);
            }
        }
        __syncthreads();
    }

    // ---- denominator = O[q][31] (lanes lc==15 of nj=1); broadcast + store
    #pragma unroll
    for (int mi = 0; mi < 4; ++mi) {
        int y = wi * 16 + w * 4 + mi;
        #pragma unroll
        for (int r = 0; r < 4; ++r) {
            float denom = __shfl(oacc[mi][1][r], lane | 15);
            float inv = 1.f / denom;
            int x = wj * 16 + lg * 4 + r;
            long grow = (long)(b * 256 + y) * 256 + x;
            #pragma unroll
            for (int nj = 0; nj < 2; ++nj) {
                int d = nj * 16 + lc;
                obuf[grow * 192 + head * 32 + d] = f2bf(d < 30 ? oacc[mi][nj][r] * inv : 0.f);
            }
        }
    }
}

// ---------------------------------------------------------------------------
extern "C" void kernel_launch(void* const* d_in, const int* in_sizes, int n_in,
                              void* d_out, int out_size, void* d_ws, size_t ws_size,
                              hipStream_t stream)
{
    const float* x      = (const float*)d_in[0];
    const int*   rpi    = (const int*)d_in[1];
    const float* qkv_w  = (const float*)d_in[2];
    const float* qkv_b  = (const float*)d_in[3];
    const float* proj_w = (const float*)d_in[4];
    const float* proj_b = (const float*)d_in[5];
    const float* rpb    = (const float*)d_in[6];
    const float* ln1_g  = (const float*)d_in[7];
    const float* ln1_b  = (const float*)d_in[8];
    const float* ln2_g  = (const float*)d_in[9];
    const float* ln2_b  = (const float*)d_in[10];
    const float* w1     = (const float*)d_in[11];
    const float* b1     = (const float*)d_in[12];
    const float* w2     = (const float*)d_in[13];
    const float* b2     = (const float*)d_in[14];
    float* out = (float*)d_out;
    char* ws = (char*)d_ws;

    // ws layout (all 256-aligned)
    ushort* wq_t     = (ushort*)(ws + 0);          // 576*192*2   = 221184
    ushort* wp_t     = (ushort*)(ws + 221184);     // 192*192*2   = 73728
    ushort* w1_t     = (ushort*)(ws + 294912);     // 384*192*2   = 147456
    ushort* w2_t     = (ushort*)(ws + 442368);     // 192*384*2   = 147456
    float*  bq       = (float*)(ws + 589824);      // 576*4
    float*  bp       = (float*)(ws + 592128);      // 192*4
    float*  b1p      = (float*)(ws + 592896);      // 384*4
    float*  b2p      = (float*)(ws + 594432);      // 192*4
    float*  bias_t   = (float*)(ws + 595200);      // 6*576*256*4 = 3538944
    ushort* hbuf     = (ushort*)(ws + 4194304);    // 131072*192*2 = 50331648
    ushort* qkv      = (ushort*)(ws + 54525952);   // 131072*576*2 = 150994944 (padded layout)
    float*  x2f      = (float*)(ws + 54525952);    // overlays qkv after attention
    ushort* obuf     = (ushort*)(ws + 205520896);  // 131072*192*2 = 50331648
    ushort* g1       = (ushort*)(ws + 205520896);  // overlays obuf: 131072*384*2

    prep_kernel<<<1158, 256, 0, stream>>>(qkv_w, qkv_b, proj_w, proj_b,
                                          w1, b1, w2, b2,
                                          wq_t, wp_t, w1_t, w2_t, bq, bp, b1p, b2p);
    biasprep_kernel<<<864, 256, 0, stream>>>(rpi, rpb, bias_t);
    ln_kernel<<<32768, 256, 0, stream>>>(x, ln1_g, ln1_b, hbuf);
    gemm_kernel<192, 0><<<dim3(9, 1024), 256, 0, stream>>>(hbuf, wq_t, bq, qkv, nullptr);
    attn_kernel<<<3072, 256, 0, stream>>>(qkv, bias_t, obuf);
    gemm_kernel<192, 1><<<dim3(3, 1024), 256, 0, stream>>>(obuf, wp_t, bp, x2f, x);
    ln_kernel<<<32768, 256, 0, stream>>>(x2f, ln2_g, ln2_b, hbuf);
    gemm_kernel<192, 2><<<dim3(6, 1024), 256, 0, stream>>>(hbuf, w1_t, b1p, g1, nullptr);
    gemm_kernel<384, 1><<<dim3(3, 1024), 256, 0, stream>>>(g1, w2_t, b2p, out, x2f);
}